// Round 1
// baseline (6584.447 us; speedup 1.0000x reference)
//
#include <hip/hip_runtime.h>
#include <hip/hip_bf16.h>

// Problem constants (match reference)
#define NPTS 200000
#define BB   4
#define C3D  64
#define C2D  128
#define HH   96
#define WW   312
#define MID  128
#define OUTC 128

// ws layout (floats)
#define IMG_T_ELEMS (BB*HH*WW*C2D)          // 15,335,424
#define STATS_OFF   IMG_T_ELEMS
#define STATS_N     (4*128*32)              // sum1,ssq1,sum2,ssq2 : 16384
#define DERIVED_OFF (STATS_OFF + STATS_N)   // s1,sh1,s2,sh2 : 512

// ---------------------------------------------------------------------------
// K1: transpose image (B,C,H,W) -> (B,H,W,C) and zero the stats buffers
// ---------------------------------------------------------------------------
__global__ __launch_bounds__(256) void k_transpose(const float* __restrict__ img,
                                                   float* __restrict__ img_t,
                                                   float* __restrict__ stats) {
    __shared__ float tile[32][33];
    int flat = blockIdx.x * 256 + threadIdx.x;
    if (flat < STATS_N) stats[flat] = 0.f;

    int bid = blockIdx.x;
    int ct = bid & 3;  bid >>= 2;          // 4 channel tiles
    int wt = bid % 10; bid /= 10;          // 10 width tiles (312 -> 10*32)
    int h  = bid % HH;
    int b  = bid / HH;
    int tx = threadIdx.x & 31, ty = threadIdx.x >> 5;   // 32 x 8
    int w0 = wt * 32, c0 = ct * 32;

    #pragma unroll
    for (int i = 0; i < 4; i++) {
        int c = c0 + ty + 8 * i;
        int w = w0 + tx;
        float v = 0.f;
        if (w < WW) v = img[((b * C2D + c) * HH + h) * WW + w];
        tile[ty + 8 * i][tx] = v;
    }
    __syncthreads();
    #pragma unroll
    for (int i = 0; i < 4; i++) {
        int w = w0 + ty + 8 * i;
        int c = c0 + tx;
        if (w < WW) img_t[((b * HH + h) * WW + w) * C2D + c] = tile[tx][ty + 8 * i];
    }
}

// ---------------------------------------------------------------------------
// K2: BN1 stats — compute h_pre = x@w1^T + b1 per row; accumulate sum/sumsq
// block = 256 thr, 64 rows; thread: r = t&63, 32 channels (cg = t>>6)
// ---------------------------------------------------------------------------
__global__ __launch_bounds__(256) void k_stats1(const float* __restrict__ x,
                                                const float* __restrict__ w1,
                                                const float* __restrict__ b1,
                                                float* __restrict__ sum1,
                                                float* __restrict__ ssq1) {
    __shared__ float xs[64 * 68];
    int t = threadIdx.x;
    int n0 = blockIdx.x * 64;
    const float4* xg = (const float4*)(x + (long)n0 * C3D);
    #pragma unroll
    for (int i = 0; i < 4; i++) {
        int f4 = t + 256 * i;               // 1024 float4 = 64 rows * 16
        int r = f4 >> 4, k4 = f4 & 15;
        *(float4*)(xs + r * 68 + k4 * 4) = xg[f4];
    }
    __syncthreads();

    int r = t & 63, cg = t >> 6;            // 4 groups * 32 ch
    float acc[32];
    #pragma unroll
    for (int cc = 0; cc < 32; cc++) acc[cc] = 0.f;
    #pragma unroll
    for (int k4 = 0; k4 < 16; k4++) {
        float4 xv = *(const float4*)(xs + r * 68 + k4 * 4);
        #pragma unroll
        for (int cc = 0; cc < 32; cc++) {
            float4 wv = *(const float4*)(w1 + (cg * 32 + cc) * C3D + k4 * 4);
            acc[cc] += xv.x * wv.x + xv.y * wv.y + xv.z * wv.z + xv.w * wv.w;
        }
    }
    int slot = blockIdx.x & 31;
    #pragma unroll
    for (int cc = 0; cc < 32; cc++) {
        float h = acc[cc] + b1[cg * 32 + cc];
        float sq = h * h;
        #pragma unroll
        for (int m = 1; m < 64; m <<= 1) {
            h  += __shfl_xor(h, m, 64);
            sq += __shfl_xor(sq, m, 64);
        }
        if (r == cc)      atomicAdd(&sum1[(cg * 32 + cc) * 32 + slot], h);
        if (r == cc + 32) atomicAdd(&ssq1[(cg * 32 + cc) * 32 + slot], sq);
    }
}

// ---------------------------------------------------------------------------
// K3/K5: finalize BN scale/shift from slotted sums
// ---------------------------------------------------------------------------
__global__ void k_finalize(const float* __restrict__ sum, const float* __restrict__ ssq,
                           const float* __restrict__ g, const float* __restrict__ b,
                           float* __restrict__ s, float* __restrict__ sh) {
    int c = threadIdx.x;   // 128
    float S = 0.f, Q = 0.f;
    for (int i = 0; i < 32; i++) { S += sum[c * 32 + i]; Q += ssq[c * 32 + i]; }
    const float invN = 1.f / (float)NPTS;
    float m = S * invN;
    float v = Q * invN - m * m;
    float sc = g[c] * rsqrtf(v + 1e-5f);
    s[c] = sc;
    sh[c] = b[c] - m * sc;
}

// ---------------------------------------------------------------------------
// K4: fused main kernel, 32 rows per block, 256 threads
// ---------------------------------------------------------------------------
__global__ __launch_bounds__(256) void k_main(
    const float* __restrict__ x, const int* __restrict__ coords,
    const float* __restrict__ img_t, const float* __restrict__ P2,
    const float* __restrict__ w1, const float* __restrict__ b1,
    const float* __restrict__ bn1s, const float* __restrict__ bn1sh,
    const float* __restrict__ w2, const float* __restrict__ b2,
    const float* __restrict__ aw1, const float* __restrict__ ab1,
    const float* __restrict__ aw2, const float* __restrict__ ab2,
    const float* __restrict__ fw, const float* __restrict__ fb,
    float* __restrict__ out, float* __restrict__ sum2, float* __restrict__ ssq2) {

    __shared__ float comb[32 * 260];   // [r][0:128)=vfeat, [128:256)=ifeat (pitch 260)
    __shared__ float buf1[32 * 132];   // xs (pitch 68) -> h -> att1 -> out staging (pitch 132)
    __shared__ int   poff[32 * 4];
    __shared__ float pwgt[32 * 4];
    __shared__ float a_s[32];

    int t = threadIdx.x;
    int n0 = blockIdx.x * 32;

    // Phase A: stage x (32 rows x 64) into buf1 with pitch 68
    {
        const float4* xg = (const float4*)(x + (long)n0 * C3D);
        #pragma unroll
        for (int i = 0; i < 2; i++) {
            int f4 = t + 256 * i;          // 512 float4
            int r = f4 >> 4, k4 = f4 & 15;
            *(float4*)(buf1 + r * 68 + k4 * 4) = xg[f4];
        }
    }
    // Phase B: projection + bilinear setup (threads 0..31, one row each)
    if (t < 32) {
        int n = n0 + t;
        int b = coords[n * 4 + 0];
        float p0 = (float)coords[n * 4 + 1] * 0.05f;
        float p1 = (float)coords[n * 4 + 2] * 0.05f - 40.f;
        float p2 = (float)coords[n * 4 + 3] * 0.1f - 3.f;
        const float* P = P2 + b * 12;
        float cam0 = P[0] * p0 + P[1] * p1 + P[2]  * p2 + P[3];
        float cam1 = P[4] * p0 + P[5] * p1 + P[6]  * p2 + P[7];
        float cam2 = P[8] * p0 + P[9] * p1 + P[10] * p2 + P[11];
        float d = cam2 + 1e-8f;
        float px = cam0 / d, py = cam1 / d;
        float gx = fminf(fmaxf(px / (float)WW * 2.f - 1.f, -1.f), 1.f);
        float gy = fminf(fmaxf(py / (float)HH * 2.f - 1.f, -1.f), 1.f);
        float ix = ((gx + 1.f) * (float)WW - 1.f) * 0.5f;
        float iy = ((gy + 1.f) * (float)HH - 1.f) * 0.5f;
        float x0f = floorf(ix), y0f = floorf(iy);
        float wx = ix - x0f, wy = iy - y0f;
        int x0 = (int)x0f, y0 = (int)y0f;
        #pragma unroll
        for (int j = 0; j < 4; j++) {
            int xc = x0 + (j & 1), yc = y0 + (j >> 1);
            float wgt = ((j & 1) ? wx : 1.f - wx) * ((j >> 1) ? wy : 1.f - wy);
            bool valid = (xc >= 0) && (xc < WW) && (yc >= 0) && (yc < HH);
            int xcc = min(max(xc, 0), WW - 1), ycc = min(max(yc, 0), HH - 1);
            poff[t * 4 + j] = ((b * HH + ycc) * WW + xcc) * C2D;
            pwgt[t * 4 + j] = valid ? wgt : 0.f;
        }
    }
    __syncthreads();

    int r = t & 31, cg = t >> 5;           // 8 groups * 16 channels

    // Phase A2: GEMM1 + BN1 + relu -> hreg
    float hreg[16];
    {
        float acc[16];
        #pragma unroll
        for (int cc = 0; cc < 16; cc++) acc[cc] = 0.f;
        #pragma unroll
        for (int k4 = 0; k4 < 16; k4++) {
            float4 xv = *(const float4*)(buf1 + r * 68 + k4 * 4);
            #pragma unroll
            for (int cc = 0; cc < 16; cc++) {
                float4 wv = *(const float4*)(w1 + (cg * 16 + cc) * C3D + k4 * 4);
                acc[cc] += xv.x * wv.x + xv.y * wv.y + xv.z * wv.z + xv.w * wv.w;
            }
        }
        #pragma unroll
        for (int cc = 0; cc < 16; cc++) {
            int c = cg * 16 + cc;
            float hp = acc[cc] + b1[c];
            hreg[cc] = fmaxf(hp * bn1s[c] + bn1sh[c], 0.f);
        }
    }
    __syncthreads();                        // all xs reads done
    #pragma unroll
    for (int cc = 0; cc < 16; cc++) buf1[r * 132 + cg * 16 + cc] = hreg[cc];
    __syncthreads();

    // Phase A3: GEMM2 -> vfeat -> comb[:, :128]
    {
        float acc[16];
        #pragma unroll
        for (int cc = 0; cc < 16; cc++) acc[cc] = b2[cg * 16 + cc];
        #pragma unroll
        for (int k4 = 0; k4 < 32; k4++) {
            float4 hv = *(const float4*)(buf1 + r * 132 + k4 * 4);
            #pragma unroll
            for (int cc = 0; cc < 16; cc++) {
                float4 wv = *(const float4*)(w2 + (cg * 16 + cc) * MID + k4 * 4);
                acc[cc] += hv.x * wv.x + hv.y * wv.y + hv.z * wv.z + hv.w * wv.w;
            }
        }
        #pragma unroll
        for (int cc = 0; cc < 16; cc++) comb[r * 260 + cg * 16 + cc] = acc[cc];
    }

    // Phase C: bilinear gather -> comb[:, 128:256)  (r2 = t/8, 16 ch per thread)
    {
        int r2 = t >> 3, sc = t & 7;
        float acc[16];
        #pragma unroll
        for (int i = 0; i < 16; i++) acc[i] = 0.f;
        #pragma unroll
        for (int j = 0; j < 4; j++) {
            float wgt = pwgt[r2 * 4 + j];
            const float4* src = (const float4*)(img_t + poff[r2 * 4 + j] + sc * 16);
            #pragma unroll
            for (int q = 0; q < 4; q++) {
                float4 v = src[q];
                acc[q * 4 + 0] += wgt * v.x;
                acc[q * 4 + 1] += wgt * v.y;
                acc[q * 4 + 2] += wgt * v.z;
                acc[q * 4 + 3] += wgt * v.w;
            }
        }
        #pragma unroll
        for (int i = 0; i < 16; i++) comb[r2 * 260 + 128 + sc * 16 + i] = acc[i];
    }
    __syncthreads();

    // Phase D: att1 GEMM + relu -> buf1 (pitch 132)
    {
        float acc[16];
        #pragma unroll
        for (int cc = 0; cc < 16; cc++) acc[cc] = ab1[cg * 16 + cc];
        #pragma unroll
        for (int k4 = 0; k4 < 64; k4++) {
            float4 cv = *(const float4*)(comb + r * 260 + k4 * 4);
            #pragma unroll
            for (int cc = 0; cc < 16; cc++) {
                float4 wv = *(const float4*)(aw1 + (cg * 16 + cc) * 256 + k4 * 4);
                acc[cc] += cv.x * wv.x + cv.y * wv.y + cv.z * wv.z + cv.w * wv.w;
            }
        }
        #pragma unroll
        for (int cc = 0; cc < 16; cc++) buf1[r * 132 + cg * 16 + cc] = fmaxf(acc[cc], 0.f);
    }
    __syncthreads();

    // Phase E: att2 + sigmoid (threads 0..31)
    if (t < 32) {
        float acc = ab2[0];
        for (int k = 0; k < 128; k++) acc += buf1[t * 132 + k] * aw2[k];
        a_s[t] = 1.f / (1.f + expf(-acc));
    }
    __syncthreads();

    // Phase E2: gate comb in place: [:,0:128) *= a, [:,128:256) *= (1-a)
    #pragma unroll
    for (int i = 0; i < 32; i++) {
        comb[i * 260 + t] *= (t < 128) ? a_s[i] : (1.f - a_s[i]);
    }
    __syncthreads();

    // Phase F: fusion GEMM -> buf1 staging
    {
        float acc[16];
        #pragma unroll
        for (int cc = 0; cc < 16; cc++) acc[cc] = fb[cg * 16 + cc];
        #pragma unroll
        for (int k4 = 0; k4 < 64; k4++) {
            float4 cv = *(const float4*)(comb + r * 260 + k4 * 4);
            #pragma unroll
            for (int cc = 0; cc < 16; cc++) {
                float4 wv = *(const float4*)(fw + (cg * 16 + cc) * 256 + k4 * 4);
                acc[cc] += cv.x * wv.x + cv.y * wv.y + cv.z * wv.z + cv.w * wv.w;
            }
        }
        __syncthreads();                    // att1 reads (phase E) long done
        #pragma unroll
        for (int cc = 0; cc < 16; cc++) buf1[r * 132 + cg * 16 + cc] = acc[cc];
    }
    __syncthreads();

    // Phase G: coalesced store of pre-BN output + BN2 stats
    {
        int r2 = t >> 3, sc = t & 7;
        float4* og = (float4*)(out + (long)n0 * OUTC);
        #pragma unroll
        for (int q = 0; q < 4; q++) {
            float4 v = *(const float4*)(buf1 + r2 * 132 + sc * 16 + q * 4);
            og[r2 * 32 + sc * 4 + q] = v;
        }
    }
    {
        int slot = blockIdx.x & 31;
        if (t < 128) {
            float S = 0.f;
            #pragma unroll
            for (int rr = 0; rr < 32; rr++) S += buf1[rr * 132 + t];
            atomicAdd(&sum2[t * 32 + slot], S);
        } else {
            int c = t - 128;
            float Q = 0.f;
            #pragma unroll
            for (int rr = 0; rr < 32; rr++) { float v = buf1[rr * 132 + c]; Q += v * v; }
            atomicAdd(&ssq2[c * 32 + slot], Q);
        }
    }
}

// ---------------------------------------------------------------------------
// K6: in-place BN2 + relu on d_out
// ---------------------------------------------------------------------------
__global__ __launch_bounds__(256) void k_bnf(float* __restrict__ out,
                                             const float* __restrict__ s,
                                             const float* __restrict__ sh) {
    long i = (long)blockIdx.x * 256 + threadIdx.x;   // over 6.4M float4
    float4* p = (float4*)out;
    float4 v = p[i];
    int c4 = (int)(i & 31);
    float4 sv  = ((const float4*)s)[c4];
    float4 shv = ((const float4*)sh)[c4];
    v.x = fmaxf(v.x * sv.x + shv.x, 0.f);
    v.y = fmaxf(v.y * sv.y + shv.y, 0.f);
    v.z = fmaxf(v.z * sv.z + shv.z, 0.f);
    v.w = fmaxf(v.w * sv.w + shv.w, 0.f);
    p[i] = v;
}

// ---------------------------------------------------------------------------
extern "C" void kernel_launch(void* const* d_in, const int* in_sizes, int n_in,
                              void* d_out, int out_size, void* d_ws, size_t ws_size,
                              hipStream_t stream) {
    const float* x      = (const float*)d_in[0];
    const int*   coords = (const int*)d_in[1];
    const float* img    = (const float*)d_in[2];
    const float* P2     = (const float*)d_in[3];
    const float* w1     = (const float*)d_in[4];
    const float* b1     = (const float*)d_in[5];
    const float* g1     = (const float*)d_in[6];
    const float* be1    = (const float*)d_in[7];
    const float* w2     = (const float*)d_in[8];
    const float* b2     = (const float*)d_in[9];
    const float* aw1    = (const float*)d_in[10];
    const float* ab1    = (const float*)d_in[11];
    const float* aw2    = (const float*)d_in[12];
    const float* ab2    = (const float*)d_in[13];
    const float* fw     = (const float*)d_in[14];
    const float* fb     = (const float*)d_in[15];
    const float* gf     = (const float*)d_in[16];
    const float* bef    = (const float*)d_in[17];
    float* out = (float*)d_out;

    float* wsf   = (float*)d_ws;
    float* img_t = wsf;
    float* sum1  = wsf + STATS_OFF;
    float* ssq1  = sum1 + 128 * 32;
    float* sum2  = ssq1 + 128 * 32;
    float* ssq2  = sum2 + 128 * 32;
    float* s1    = wsf + DERIVED_OFF;
    float* sh1   = s1 + 128;
    float* s2    = sh1 + 128;
    float* sh2   = s2 + 128;

    // K1: transpose image + zero stats (grid: 4*96*10*4 = 15360)
    k_transpose<<<BB * HH * 10 * 4, 256, 0, stream>>>(img, img_t, sum1);
    // K2: BN1 stats (200000 / 64 = 3125 blocks)
    k_stats1<<<NPTS / 64, 256, 0, stream>>>(x, w1, b1, sum1, ssq1);
    // K3: finalize BN1
    k_finalize<<<1, 128, 0, stream>>>(sum1, ssq1, g1, be1, s1, sh1);
    // K4: fused main (200000 / 32 = 6250 blocks)
    k_main<<<NPTS / 32, 256, 0, stream>>>(x, coords, img_t, P2, w1, b1, s1, sh1,
                                          w2, b2, aw1, ab1, aw2, ab2, fw, fb,
                                          out, sum2, ssq2);
    // K5: finalize BN2
    k_finalize<<<1, 128, 0, stream>>>(sum2, ssq2, gf, bef, s2, sh2);
    // K6: in-place BN2 + relu (25.6M floats / 4 / 256 = 25000 blocks)
    k_bnf<<<NPTS * OUTC / 4 / 256, 256, 0, stream>>>(out, s2, sh2);
}

// Round 2
// 2554.029 us; speedup vs baseline: 2.5781x; 2.5781x over previous
//
#include <hip/hip_runtime.h>
#include <hip/hip_bf16.h>

// Problem constants (match reference)
#define NPTS 200000
#define BB   4
#define C3D  64
#define C2D  128
#define HH   96
#define WW   312
#define MID  128
#define OUTC 128

// ws layout (floats)
#define IMG_T_ELEMS (BB*HH*WW*C2D)          // 15,335,424
#define STATS_OFF   IMG_T_ELEMS
// S (64x64=4096) | colsum (64) | sum2 (128*32) | ssq2 (128*32)
#define ZERO_N      (4096 + 64 + 128*32*2)  // 12352
#define DERIVED_OFF (STATS_OFF + ZERO_N)    // s1,sh1,s2,sh2 : 512

// ---------------------------------------------------------------------------
// K1: transpose image (B,C,H,W) -> (B,H,W,C) and zero the stats buffers
// ---------------------------------------------------------------------------
__global__ __launch_bounds__(256) void k_transpose(const float* __restrict__ img,
                                                   float* __restrict__ img_t,
                                                   float* __restrict__ stats) {
    __shared__ float tile[32][33];
    int flat = blockIdx.x * 256 + threadIdx.x;
    if (flat < ZERO_N) stats[flat] = 0.f;

    int bid = blockIdx.x;
    int ct = bid & 3;  bid >>= 2;          // 4 channel tiles
    int wt = bid % 10; bid /= 10;          // 10 width tiles (312 -> 10*32)
    int h  = bid % HH;
    int b  = bid / HH;
    int tx = threadIdx.x & 31, ty = threadIdx.x >> 5;   // 32 x 8
    int w0 = wt * 32, c0 = ct * 32;

    #pragma unroll
    for (int i = 0; i < 4; i++) {
        int c = c0 + ty + 8 * i;
        int w = w0 + tx;
        float v = 0.f;
        if (w < WW) v = img[((b * C2D + c) * HH + h) * WW + w];
        tile[ty + 8 * i][tx] = v;
    }
    __syncthreads();
    #pragma unroll
    for (int i = 0; i < 4; i++) {
        int w = w0 + ty + 8 * i;
        int c = c0 + tx;
        if (w < WW) img_t[((b * HH + h) * WW + w) * C2D + c] = tile[tx][ty + 8 * i];
    }
}

// ---------------------------------------------------------------------------
// K2: second-moment matrix S = X^T X (64x64) + column sums of X.
// 256 threads = 16x16 tile grid, each thread owns a 4x4 tile of S.
// ---------------------------------------------------------------------------
#define XTX_ROWS_PER_BLK 256
#define XTX_BLOCKS ((NPTS + XTX_ROWS_PER_BLK - 1) / XTX_ROWS_PER_BLK)   // 782

__global__ __launch_bounds__(256) void k_xtx(const float* __restrict__ x,
                                             float* __restrict__ S,
                                             float* __restrict__ colsum) {
    __shared__ float xs[64 * 68];
    int t = threadIdx.x;
    int ti = t >> 4, tj = t & 15;          // 16 x 16 thread grid
    float acc[4][4];
    #pragma unroll
    for (int a = 0; a < 4; a++)
        #pragma unroll
        for (int b = 0; b < 4; b++) acc[a][b] = 0.f;
    float csum = 0.f;

    int r0 = blockIdx.x * XTX_ROWS_PER_BLK;
    int r1 = min(r0 + XTX_ROWS_PER_BLK, NPTS);

    for (int base = r0; base < r1; base += 64) {
        int nrows = r1 - base;             // may exceed 64; clamp below
        if (nrows > 64) nrows = 64;
        __syncthreads();                   // previous tile's reads done
        const float4* xg = (const float4*)(x + (long)base * C3D);
        #pragma unroll
        for (int i = 0; i < 4; i++) {
            int f4 = t + 256 * i;          // 1024 float4 = 64 rows * 16
            int r = f4 >> 4, k4 = f4 & 15;
            float4 v = make_float4(0.f, 0.f, 0.f, 0.f);
            if (r < nrows) v = xg[f4];
            *(float4*)(xs + r * 68 + k4 * 4) = v;
        }
        __syncthreads();
        #pragma unroll 4
        for (int r = 0; r < 64; r++) {     // zero-padded rows contribute 0
            float4 av = *(const float4*)(xs + r * 68 + ti * 4);
            float4 bv = *(const float4*)(xs + r * 68 + tj * 4);
            float aa[4] = {av.x, av.y, av.z, av.w};
            float bb[4] = {bv.x, bv.y, bv.z, bv.w};
            #pragma unroll
            for (int a = 0; a < 4; a++)
                #pragma unroll
                for (int b = 0; b < 4; b++) acc[a][b] += aa[a] * bb[b];
        }
        if (t < 64) {
            #pragma unroll 8
            for (int r = 0; r < 64; r++) csum += xs[r * 68 + t];
        }
    }
    #pragma unroll
    for (int a = 0; a < 4; a++)
        #pragma unroll
        for (int b = 0; b < 4; b++)
            atomicAdd(&S[(ti * 4 + a) * 64 + tj * 4 + b], acc[a][b]);
    if (t < 64) atomicAdd(&colsum[t], csum);
}

// ---------------------------------------------------------------------------
// K3: finalize BN1 from S and colsum (algebraic BN-through-affine)
// ---------------------------------------------------------------------------
__global__ void k_finalize1(const float* __restrict__ S, const float* __restrict__ colsum,
                            const float* __restrict__ w1, const float* __restrict__ b1,
                            const float* __restrict__ g, const float* __restrict__ be,
                            float* __restrict__ s, float* __restrict__ sh) {
    __shared__ float Ss[64 * 64];
    __shared__ float cs[64];
    int t = threadIdx.x;                   // 128 threads = 128 channels
    for (int i = t; i < 4096; i += 128) Ss[i] = S[i];
    if (t < 64) cs[t] = colsum[t];
    __syncthreads();

    float w[64];
    #pragma unroll
    for (int k = 0; k < 64; k++) w[k] = w1[t * 64 + k];
    float wc = 0.f;
    #pragma unroll
    for (int k = 0; k < 64; k++) wc += w[k] * cs[k];
    float q = 0.f;
    for (int k = 0; k < 64; k++) {
        float tk = 0.f;
        #pragma unroll
        for (int l = 0; l < 64; l++) tk += Ss[k * 64 + l] * w[l];
        q += w[k] * tk;
    }
    const float invN = 1.f / (float)NPTS;
    float bc = b1[t];
    float m = wc * invN + bc;
    float Eh2 = q * invN + 2.f * bc * wc * invN + bc * bc;
    float v = Eh2 - m * m;
    float sc = g[t] * rsqrtf(v + 1e-5f);
    s[t] = sc;
    sh[t] = be[t] - m * sc;
}

// ---------------------------------------------------------------------------
// K5: finalize BN2 from slotted sums
// ---------------------------------------------------------------------------
__global__ void k_finalize(const float* __restrict__ sum, const float* __restrict__ ssq,
                           const float* __restrict__ g, const float* __restrict__ b,
                           float* __restrict__ s, float* __restrict__ sh) {
    int c = threadIdx.x;   // 128
    float S = 0.f, Q = 0.f;
    for (int i = 0; i < 32; i++) { S += sum[c * 32 + i]; Q += ssq[c * 32 + i]; }
    const float invN = 1.f / (float)NPTS;
    float m = S * invN;
    float v = Q * invN - m * m;
    float sc = g[c] * rsqrtf(v + 1e-5f);
    s[c] = sc;
    sh[c] = b[c] - m * sc;
}

// ---------------------------------------------------------------------------
// K4: fused main kernel, 32 rows per block, 256 threads
// ---------------------------------------------------------------------------
__global__ __launch_bounds__(256) void k_main(
    const float* __restrict__ x, const int* __restrict__ coords,
    const float* __restrict__ img_t, const float* __restrict__ P2,
    const float* __restrict__ w1, const float* __restrict__ b1,
    const float* __restrict__ bn1s, const float* __restrict__ bn1sh,
    const float* __restrict__ w2, const float* __restrict__ b2,
    const float* __restrict__ aw1, const float* __restrict__ ab1,
    const float* __restrict__ aw2, const float* __restrict__ ab2,
    const float* __restrict__ fw, const float* __restrict__ fb,
    float* __restrict__ out, float* __restrict__ sum2, float* __restrict__ ssq2) {

    __shared__ float comb[32 * 260];   // [r][0:128)=vfeat, [128:256)=ifeat (pitch 260)
    __shared__ float buf1[32 * 132];   // xs (pitch 68) -> h -> att1 -> out staging (pitch 132)
    __shared__ int   poff[32 * 4];
    __shared__ float pwgt[32 * 4];
    __shared__ float a_s[32];

    int t = threadIdx.x;
    int n0 = blockIdx.x * 32;

    // Phase A: stage x (32 rows x 64) into buf1 with pitch 68
    {
        const float4* xg = (const float4*)(x + (long)n0 * C3D);
        #pragma unroll
        for (int i = 0; i < 2; i++) {
            int f4 = t + 256 * i;          // 512 float4
            int r = f4 >> 4, k4 = f4 & 15;
            *(float4*)(buf1 + r * 68 + k4 * 4) = xg[f4];
        }
    }
    // Phase B: projection + bilinear setup (threads 0..31, one row each)
    if (t < 32) {
        int n = n0 + t;
        int b = coords[n * 4 + 0];
        float p0 = (float)coords[n * 4 + 1] * 0.05f;
        float p1 = (float)coords[n * 4 + 2] * 0.05f - 40.f;
        float p2 = (float)coords[n * 4 + 3] * 0.1f - 3.f;
        const float* P = P2 + b * 12;
        float cam0 = P[0] * p0 + P[1] * p1 + P[2]  * p2 + P[3];
        float cam1 = P[4] * p0 + P[5] * p1 + P[6]  * p2 + P[7];
        float cam2 = P[8] * p0 + P[9] * p1 + P[10] * p2 + P[11];
        float d = cam2 + 1e-8f;
        float px = cam0 / d, py = cam1 / d;
        float gx = fminf(fmaxf(px / (float)WW * 2.f - 1.f, -1.f), 1.f);
        float gy = fminf(fmaxf(py / (float)HH * 2.f - 1.f, -1.f), 1.f);
        float ix = ((gx + 1.f) * (float)WW - 1.f) * 0.5f;
        float iy = ((gy + 1.f) * (float)HH - 1.f) * 0.5f;
        float x0f = floorf(ix), y0f = floorf(iy);
        float wx = ix - x0f, wy = iy - y0f;
        int x0 = (int)x0f, y0 = (int)y0f;
        #pragma unroll
        for (int j = 0; j < 4; j++) {
            int xc = x0 + (j & 1), yc = y0 + (j >> 1);
            float wgt = ((j & 1) ? wx : 1.f - wx) * ((j >> 1) ? wy : 1.f - wy);
            bool valid = (xc >= 0) && (xc < WW) && (yc >= 0) && (yc < HH);
            int xcc = min(max(xc, 0), WW - 1), ycc = min(max(yc, 0), HH - 1);
            poff[t * 4 + j] = ((b * HH + ycc) * WW + xcc) * C2D;
            pwgt[t * 4 + j] = valid ? wgt : 0.f;
        }
    }
    __syncthreads();

    int r = t & 31, cg = t >> 5;           // 8 groups * 16 channels

    // Phase A2: GEMM1 + BN1 + relu -> hreg
    float hreg[16];
    {
        float acc[16];
        #pragma unroll
        for (int cc = 0; cc < 16; cc++) acc[cc] = 0.f;
        #pragma unroll
        for (int k4 = 0; k4 < 16; k4++) {
            float4 xv = *(const float4*)(buf1 + r * 68 + k4 * 4);
            #pragma unroll
            for (int cc = 0; cc < 16; cc++) {
                float4 wv = *(const float4*)(w1 + (cg * 16 + cc) * C3D + k4 * 4);
                acc[cc] += xv.x * wv.x + xv.y * wv.y + xv.z * wv.z + xv.w * wv.w;
            }
        }
        #pragma unroll
        for (int cc = 0; cc < 16; cc++) {
            int c = cg * 16 + cc;
            float hp = acc[cc] + b1[c];
            hreg[cc] = fmaxf(hp * bn1s[c] + bn1sh[c], 0.f);
        }
    }
    __syncthreads();                        // all xs reads done
    #pragma unroll
    for (int cc = 0; cc < 16; cc++) buf1[r * 132 + cg * 16 + cc] = hreg[cc];
    __syncthreads();

    // Phase A3: GEMM2 -> vfeat -> comb[:, :128]
    {
        float acc[16];
        #pragma unroll
        for (int cc = 0; cc < 16; cc++) acc[cc] = b2[cg * 16 + cc];
        #pragma unroll
        for (int k4 = 0; k4 < 32; k4++) {
            float4 hv = *(const float4*)(buf1 + r * 132 + k4 * 4);
            #pragma unroll
            for (int cc = 0; cc < 16; cc++) {
                float4 wv = *(const float4*)(w2 + (cg * 16 + cc) * MID + k4 * 4);
                acc[cc] += hv.x * wv.x + hv.y * wv.y + hv.z * wv.z + hv.w * wv.w;
            }
        }
        #pragma unroll
        for (int cc = 0; cc < 16; cc++) comb[r * 260 + cg * 16 + cc] = acc[cc];
    }

    // Phase C: bilinear gather -> comb[:, 128:256)  (r2 = t/8, 16 ch per thread)
    {
        int r2 = t >> 3, sc = t & 7;
        float acc[16];
        #pragma unroll
        for (int i = 0; i < 16; i++) acc[i] = 0.f;
        #pragma unroll
        for (int j = 0; j < 4; j++) {
            float wgt = pwgt[r2 * 4 + j];
            const float4* src = (const float4*)(img_t + poff[r2 * 4 + j] + sc * 16);
            #pragma unroll
            for (int q = 0; q < 4; q++) {
                float4 v = src[q];
                acc[q * 4 + 0] += wgt * v.x;
                acc[q * 4 + 1] += wgt * v.y;
                acc[q * 4 + 2] += wgt * v.z;
                acc[q * 4 + 3] += wgt * v.w;
            }
        }
        #pragma unroll
        for (int i = 0; i < 16; i++) comb[r2 * 260 + 128 + sc * 16 + i] = acc[i];
    }
    __syncthreads();

    // Phase D: att1 GEMM + relu -> buf1 (pitch 132)
    {
        float acc[16];
        #pragma unroll
        for (int cc = 0; cc < 16; cc++) acc[cc] = ab1[cg * 16 + cc];
        #pragma unroll
        for (int k4 = 0; k4 < 64; k4++) {
            float4 cv = *(const float4*)(comb + r * 260 + k4 * 4);
            #pragma unroll
            for (int cc = 0; cc < 16; cc++) {
                float4 wv = *(const float4*)(aw1 + (cg * 16 + cc) * 256 + k4 * 4);
                acc[cc] += cv.x * wv.x + cv.y * wv.y + cv.z * wv.z + cv.w * wv.w;
            }
        }
        #pragma unroll
        for (int cc = 0; cc < 16; cc++) buf1[r * 132 + cg * 16 + cc] = fmaxf(acc[cc], 0.f);
    }
    __syncthreads();

    // Phase E: att2 + sigmoid (threads 0..31)
    if (t < 32) {
        float acc = ab2[0];
        for (int k = 0; k < 128; k++) acc += buf1[t * 132 + k] * aw2[k];
        a_s[t] = 1.f / (1.f + expf(-acc));
    }
    __syncthreads();

    // Phase E2: gate comb in place: [:,0:128) *= a, [:,128:256) *= (1-a)
    #pragma unroll
    for (int i = 0; i < 32; i++) {
        comb[i * 260 + t] *= (t < 128) ? a_s[i] : (1.f - a_s[i]);
    }
    __syncthreads();

    // Phase F: fusion GEMM -> buf1 staging
    {
        float acc[16];
        #pragma unroll
        for (int cc = 0; cc < 16; cc++) acc[cc] = fb[cg * 16 + cc];
        #pragma unroll
        for (int k4 = 0; k4 < 64; k4++) {
            float4 cv = *(const float4*)(comb + r * 260 + k4 * 4);
            #pragma unroll
            for (int cc = 0; cc < 16; cc++) {
                float4 wv = *(const float4*)(fw + (cg * 16 + cc) * 256 + k4 * 4);
                acc[cc] += cv.x * wv.x + cv.y * wv.y + cv.z * wv.z + cv.w * wv.w;
            }
        }
        __syncthreads();                    // att1 reads (phase E) long done
        #pragma unroll
        for (int cc = 0; cc < 16; cc++) buf1[r * 132 + cg * 16 + cc] = acc[cc];
    }
    __syncthreads();

    // Phase G: coalesced store of pre-BN output + BN2 stats
    {
        int r2 = t >> 3, sc = t & 7;
        float4* og = (float4*)(out + (long)n0 * OUTC);
        #pragma unroll
        for (int q = 0; q < 4; q++) {
            float4 v = *(const float4*)(buf1 + r2 * 132 + sc * 16 + q * 4);
            og[r2 * 32 + sc * 4 + q] = v;
        }
    }
    {
        int slot = blockIdx.x & 31;
        if (t < 128) {
            float S = 0.f;
            #pragma unroll
            for (int rr = 0; rr < 32; rr++) S += buf1[rr * 132 + t];
            atomicAdd(&sum2[t * 32 + slot], S);
        } else {
            int c = t - 128;
            float Q = 0.f;
            #pragma unroll
            for (int rr = 0; rr < 32; rr++) { float v = buf1[rr * 132 + c]; Q += v * v; }
            atomicAdd(&ssq2[c * 32 + slot], Q);
        }
    }
}

// ---------------------------------------------------------------------------
// K6: in-place BN2 + relu on d_out
// ---------------------------------------------------------------------------
__global__ __launch_bounds__(256) void k_bnf(float* __restrict__ out,
                                             const float* __restrict__ s,
                                             const float* __restrict__ sh) {
    long i = (long)blockIdx.x * 256 + threadIdx.x;   // over 6.4M float4
    float4* p = (float4*)out;
    float4 v = p[i];
    int c4 = (int)(i & 31);
    float4 sv  = ((const float4*)s)[c4];
    float4 shv = ((const float4*)sh)[c4];
    v.x = fmaxf(v.x * sv.x + shv.x, 0.f);
    v.y = fmaxf(v.y * sv.y + shv.y, 0.f);
    v.z = fmaxf(v.z * sv.z + shv.z, 0.f);
    v.w = fmaxf(v.w * sv.w + shv.w, 0.f);
    p[i] = v;
}

// ---------------------------------------------------------------------------
extern "C" void kernel_launch(void* const* d_in, const int* in_sizes, int n_in,
                              void* d_out, int out_size, void* d_ws, size_t ws_size,
                              hipStream_t stream) {
    const float* x      = (const float*)d_in[0];
    const int*   coords = (const int*)d_in[1];
    const float* img    = (const float*)d_in[2];
    const float* P2     = (const float*)d_in[3];
    const float* w1     = (const float*)d_in[4];
    const float* b1     = (const float*)d_in[5];
    const float* g1     = (const float*)d_in[6];
    const float* be1    = (const float*)d_in[7];
    const float* w2     = (const float*)d_in[8];
    const float* b2     = (const float*)d_in[9];
    const float* aw1    = (const float*)d_in[10];
    const float* ab1    = (const float*)d_in[11];
    const float* aw2    = (const float*)d_in[12];
    const float* ab2    = (const float*)d_in[13];
    const float* fw     = (const float*)d_in[14];
    const float* fb     = (const float*)d_in[15];
    const float* gf     = (const float*)d_in[16];
    const float* bef    = (const float*)d_in[17];
    float* out = (float*)d_out;

    float* wsf   = (float*)d_ws;
    float* img_t = wsf;
    float* S     = wsf + STATS_OFF;
    float* csum  = S + 4096;
    float* sum2  = csum + 64;
    float* ssq2  = sum2 + 128 * 32;
    float* s1    = wsf + DERIVED_OFF;
    float* sh1   = s1 + 128;
    float* s2    = sh1 + 128;
    float* sh2   = s2 + 128;

    // K1: transpose image + zero stats (grid: 4*96*10*4 = 15360)
    k_transpose<<<BB * HH * 10 * 4, 256, 0, stream>>>(img, img_t, S);
    // K2: X^T X + colsum (782 blocks)
    k_xtx<<<XTX_BLOCKS, 256, 0, stream>>>(x, S, csum);
    // K3: finalize BN1 (algebraic)
    k_finalize1<<<1, 128, 0, stream>>>(S, csum, w1, b1, g1, be1, s1, sh1);
    // K4: fused main (200000 / 32 = 6250 blocks)
    k_main<<<NPTS / 32, 256, 0, stream>>>(x, coords, img_t, P2, w1, b1, s1, sh1,
                                          w2, b2, aw1, ab1, aw2, ab2, fw, fb,
                                          out, sum2, ssq2);
    // K5: finalize BN2
    k_finalize<<<1, 128, 0, stream>>>(sum2, ssq2, gf, bef, s2, sh2);
    // K6: in-place BN2 + relu (25.6M floats / 4 / 256 = 25000 blocks)
    k_bnf<<<NPTS * OUTC / 4 / 256, 256, 0, stream>>>(out, s2, sh2);
}

// Round 6
// 746.528 us; speedup vs baseline: 8.8201x; 3.4212x over previous
//
#include <hip/hip_runtime.h>
#include <hip/hip_bf16.h>

// Problem constants (match reference)
#define NPTS 200000
#define BB   4
#define C3D  64
#define C2D  128
#define HH   96
#define WW   312
#define MID  128
#define OUTC 128

// bf16 weight sub-offsets (ushort elements)
#define WB_W1   0
#define WB_W2   8192
#define WB_AW1  24576
#define WB_AW2  57344
#define WB_FW   57472
#define WB_TOTAL 90240                     // ushorts = 45120 floats

// Fixed-point scale for deterministic integer atomics
#define FXS 1048576.0f
#define FXI (1.0 / 1048576.0)

// ws layout (float offsets). All stats are u64 fixed-point (2 floats each).
#define WS_S64    45120                    // 4096 u64  -> 8192 floats
#define WS_CS64   53312                    // 64 u64    -> 128 floats
#define WS_SUM64  53440                    // 128*16 u64-> 4096 floats
#define WS_SSQ64  57536                    // 128*16 u64-> 4096 floats
#define ZERO_N    16512                    // floats to zero: 45120..61632
#define WS_DERIV  61632                    // s1,sh1,s2,sh2 : 512
#define WS_IMG    62144                    // bf16 image, 15,335,424 ushorts

typedef __attribute__((ext_vector_type(8))) short s16x8;
typedef __attribute__((ext_vector_type(4))) float f32x4;

__device__ __forceinline__ ushort f2bf(float f) {
    unsigned u = __float_as_uint(f);
    unsigned r = (u + 0x7FFFu + ((u >> 16) & 1u)) >> 16;   // RNE
    return (ushort)r;
}
__device__ __forceinline__ float bf2f(ushort u) {
    return __uint_as_float(((unsigned)u) << 16);
}
__device__ __forceinline__ void atomic_fx(unsigned long long* p, float v) {
    atomicAdd(p, (unsigned long long)(long long)llrintf(v * FXS));
}

// ---------------------------------------------------------------------------
// K1: transpose image (B,C,H,W) -> (B,H,W,C) bf16, and zero the stats region
// ---------------------------------------------------------------------------
__global__ __launch_bounds__(256) void k_transpose(const float* __restrict__ img,
                                                   ushort* __restrict__ img_bf,
                                                   float* __restrict__ stats) {
    __shared__ float tile[32][33];
    int flat = blockIdx.x * 256 + threadIdx.x;
    if (flat < ZERO_N) stats[flat] = 0.f;

    int bid = blockIdx.x;
    int ct = bid & 3;  bid >>= 2;          // 4 channel tiles
    int wt = bid % 10; bid /= 10;          // 10 width tiles
    int h  = bid % HH;
    int b  = bid / HH;
    int tx = threadIdx.x & 31, ty = threadIdx.x >> 5;   // 32 x 8
    int w0 = wt * 32, c0 = ct * 32;

    #pragma unroll
    for (int i = 0; i < 4; i++) {
        int c = c0 + ty + 8 * i;
        int w = w0 + tx;
        float v = 0.f;
        if (w < WW) v = img[((b * C2D + c) * HH + h) * WW + w];
        tile[ty + 8 * i][tx] = v;
    }
    __syncthreads();
    #pragma unroll
    for (int i = 0; i < 4; i++) {
        int w = w0 + ty + 8 * i;
        int c = c0 + tx;
        if (w < WW) img_bf[((b * HH + h) * WW + w) * C2D + c] = f2bf(tile[tx][ty + 8 * i]);
    }
}

// ---------------------------------------------------------------------------
// K1b: convert weights to bf16 (row-major unchanged)
// ---------------------------------------------------------------------------
__global__ __launch_bounds__(256) void k_prepw(const float* __restrict__ w1,
                                               const float* __restrict__ w2,
                                               const float* __restrict__ aw1,
                                               const float* __restrict__ aw2,
                                               const float* __restrict__ fw,
                                               ushort* __restrict__ wb) {
    int i = blockIdx.x * 256 + threadIdx.x;
    if (i >= WB_TOTAL) return;
    float v;
    if      (i < WB_W2)  v = w1[i - WB_W1];
    else if (i < WB_AW1) v = w2[i - WB_W2];
    else if (i < WB_AW2) v = aw1[i - WB_AW1];
    else if (i < WB_FW)  v = aw2[i - WB_AW2];
    else                 v = fw[i - WB_FW];
    wb[i] = f2bf(v);
}

// ---------------------------------------------------------------------------
// K2: X^T X (64x64) + colsum, fixed-point u64 atomics (deterministic)
// ---------------------------------------------------------------------------
#define XTX_ROWS_PER_BLK 256
#define XTX_BLOCKS ((NPTS + XTX_ROWS_PER_BLK - 1) / XTX_ROWS_PER_BLK)   // 782

__global__ __launch_bounds__(256) void k_xtx(const float* __restrict__ x,
                                             unsigned long long* __restrict__ S64,
                                             unsigned long long* __restrict__ cs64) {
    __shared__ float xs[64 * 68];
    int t = threadIdx.x;
    int ti = t >> 4, tj = t & 15;
    float acc[4][4];
    #pragma unroll
    for (int a = 0; a < 4; a++)
        #pragma unroll
        for (int b = 0; b < 4; b++) acc[a][b] = 0.f;
    float csum = 0.f;

    int r0 = blockIdx.x * XTX_ROWS_PER_BLK;
    int r1 = min(r0 + XTX_ROWS_PER_BLK, NPTS);

    for (int base = r0; base < r1; base += 64) {
        int nrows = r1 - base;
        if (nrows > 64) nrows = 64;
        __syncthreads();
        const float4* xg = (const float4*)(x + (long)base * C3D);
        #pragma unroll
        for (int i = 0; i < 4; i++) {
            int f4 = t + 256 * i;
            int r = f4 >> 4, k4 = f4 & 15;
            float4 v = make_float4(0.f, 0.f, 0.f, 0.f);
            if (r < nrows) v = xg[f4];
            *(float4*)(xs + r * 68 + k4 * 4) = v;
        }
        __syncthreads();
        #pragma unroll 4
        for (int r = 0; r < 64; r++) {
            float4 av = *(const float4*)(xs + r * 68 + ti * 4);
            float4 bv = *(const float4*)(xs + r * 68 + tj * 4);
            float aa[4] = {av.x, av.y, av.z, av.w};
            float bb[4] = {bv.x, bv.y, bv.z, bv.w};
            #pragma unroll
            for (int a = 0; a < 4; a++)
                #pragma unroll
                for (int b = 0; b < 4; b++) acc[a][b] += aa[a] * bb[b];
        }
        if (t < 64) {
            #pragma unroll 8
            for (int r = 0; r < 64; r++) csum += xs[r * 68 + t];
        }
    }
    #pragma unroll
    for (int a = 0; a < 4; a++)
        #pragma unroll
        for (int b = 0; b < 4; b++)
            atomic_fx(&S64[(ti * 4 + a) * 64 + tj * 4 + b], acc[a][b]);
    if (t < 64) atomic_fx(&cs64[t], csum);
}

// ---------------------------------------------------------------------------
// K3: finalize BN1 from S64/cs64 (algebraic BN-through-affine, b1 folded)
// ---------------------------------------------------------------------------
__global__ void k_finalize1(const unsigned long long* __restrict__ S64,
                            const unsigned long long* __restrict__ cs64,
                            const float* __restrict__ w1, const float* __restrict__ b1,
                            const float* __restrict__ g, const float* __restrict__ be,
                            float* __restrict__ s, float* __restrict__ sh) {
    __shared__ float Ss[64 * 64];
    __shared__ float cs[64];
    int t = threadIdx.x;                   // 128 threads = 128 channels
    for (int i = t; i < 4096; i += 128)
        Ss[i] = (float)((double)(long long)S64[i] * FXI);
    if (t < 64) cs[t] = (float)((double)(long long)cs64[t] * FXI);
    __syncthreads();

    float w[64];
    #pragma unroll
    for (int k = 0; k < 64; k++) w[k] = w1[t * 64 + k];
    float wc = 0.f;
    #pragma unroll
    for (int k = 0; k < 64; k++) wc += w[k] * cs[k];
    float q = 0.f;
    for (int k = 0; k < 64; k++) {
        float tk = 0.f;
        #pragma unroll
        for (int l = 0; l < 64; l++) tk += Ss[k * 64 + l] * w[l];
        q += w[k] * tk;
    }
    const float invN = 1.f / (float)NPTS;
    float bc = b1[t];
    float m = wc * invN + bc;
    float Eh2 = q * invN + 2.f * bc * wc * invN + bc * bc;
    float v = Eh2 - m * m;
    float sc = g[t] * rsqrtf(v + 1e-5f);
    s[t] = sc;
    sh[t] = be[t] - (wc * invN) * sc;      // (b1 - m) * sc + be
}

// ---------------------------------------------------------------------------
// K5: finalize BN2 from 16-slot u64 fixed-point sums (fixed-order reduce)
// ---------------------------------------------------------------------------
__global__ void k_finalize(const unsigned long long* __restrict__ sum64,
                           const unsigned long long* __restrict__ ssq64,
                           const float* __restrict__ g, const float* __restrict__ b,
                           float* __restrict__ s, float* __restrict__ sh) {
    int c = threadIdx.x;   // 128
    long long si = 0, qi = 0;
    for (int i = 0; i < 16; i++) {
        si += (long long)sum64[c * 16 + i];
        qi += (long long)ssq64[c * 16 + i];
    }
    float S = (float)((double)si * FXI);
    float Q = (float)((double)qi * FXI);
    const float invN = 1.f / (float)NPTS;
    float m = S * invN;
    float v = Q * invN - m * m;
    float sc = g[c] * rsqrtf(v + 1e-5f);
    s[c] = sc;
    sh[c] = b[c] - m * sc;
}

// ---------------------------------------------------------------------------
// K4: fused main kernel (MFMA bf16), 64 rows/block, 256 threads = 4 waves.
// A-frag (16x16x32): lane holds A[m=lane&15][k=(lane>>4)*8+j]
// B-frag:            lane holds B[k=(lane>>4)*8+j][n=lane&15]  (row-major W)
// D:                 m=(lane>>4)*4+reg, n=lane&15
// (verified end-to-end, round 4: absmax 0.03125 on first launch)
// ---------------------------------------------------------------------------
__global__ __launch_bounds__(256, 3) void k_main(
    const float* __restrict__ x, const int* __restrict__ coords,
    const ushort* __restrict__ img_bf, const float* __restrict__ P2,
    const ushort* __restrict__ wb,
    const float* __restrict__ bn1s, const float* __restrict__ bn1sh,
    const float* __restrict__ b2, const float* __restrict__ ab1,
    const float* __restrict__ ab2, const float* __restrict__ fb,
    float* __restrict__ out,
    unsigned long long* __restrict__ sum64, unsigned long long* __restrict__ ssq64)
{
    // LDS: combs (64x264 bf16, 33792B) aliases xs (64x72 bf16) and outs (64x132 f32)
    __shared__ __align__(16) char smem[53504];
    ushort* combs = (ushort*)smem;
    float*  outs  = (float*)smem;
    ushort* xs    = (ushort*)smem;
    ushort* hs    = (ushort*)(smem + 33792);   // 64x136 bf16, 17408B
    int*    poff  = (int*)(smem + 51200);      // 64x4
    float*  pwgt  = (float*)(smem + 52224);    // 64x4
    float*  a_s   = (float*)(smem + 53248);    // 64

    const ushort* w1b  = wb + WB_W1;
    const ushort* w2b  = wb + WB_W2;
    const ushort* aw1b = wb + WB_AW1;
    const ushort* aw2b = wb + WB_AW2;
    const ushort* fwb  = wb + WB_FW;

    int t = threadIdx.x;
    int n0 = blockIdx.x * 64;
    int lane = t & 63, wv = t >> 6;
    int l15 = lane & 15, lq = lane >> 4;
    int m0 = wv * 16;

    // ---- phase 1: stage x -> xs (bf16, pitch 72); projection setup ----
    {
        const float4* xg = (const float4*)(x + (long)n0 * C3D);
        #pragma unroll
        for (int i = 0; i < 2; i++) {
            int idx8 = t + 256 * i;            // 512 groups of 8 floats
            int row = idx8 >> 3, k8 = idx8 & 7;
            float4 a = xg[idx8 * 2];
            float4 b = xg[idx8 * 2 + 1];
            s16x8 v;
            v[0] = (short)f2bf(a.x); v[1] = (short)f2bf(a.y);
            v[2] = (short)f2bf(a.z); v[3] = (short)f2bf(a.w);
            v[4] = (short)f2bf(b.x); v[5] = (short)f2bf(b.y);
            v[6] = (short)f2bf(b.z); v[7] = (short)f2bf(b.w);
            *(s16x8*)(xs + row * 72 + k8 * 8) = v;
        }
    }
    if (t < 64) {
        int n = n0 + t;
        int b = coords[n * 4 + 0];
        float p0 = (float)coords[n * 4 + 1] * 0.05f;
        float p1 = (float)coords[n * 4 + 2] * 0.05f - 40.f;
        float p2 = (float)coords[n * 4 + 3] * 0.1f - 3.f;
        const float* P = P2 + b * 12;
        float cam0 = P[0] * p0 + P[1] * p1 + P[2]  * p2 + P[3];
        float cam1 = P[4] * p0 + P[5] * p1 + P[6]  * p2 + P[7];
        float cam2 = P[8] * p0 + P[9] * p1 + P[10] * p2 + P[11];
        float d = cam2 + 1e-8f;
        float px = cam0 / d, py = cam1 / d;
        float gx = fminf(fmaxf(px / (float)WW * 2.f - 1.f, -1.f), 1.f);
        float gy = fminf(fmaxf(py / (float)HH * 2.f - 1.f, -1.f), 1.f);
        float ix = ((gx + 1.f) * (float)WW - 1.f) * 0.5f;
        float iy = ((gy + 1.f) * (float)HH - 1.f) * 0.5f;
        float x0f = floorf(ix), y0f = floorf(iy);
        float wx = ix - x0f, wy = iy - y0f;
        int x0 = (int)x0f, y0 = (int)y0f;
        #pragma unroll
        for (int j = 0; j < 4; j++) {
            int xc = x0 + (j & 1), yc = y0 + (j >> 1);
            float wgt = ((j & 1) ? wx : 1.f - wx) * ((j >> 1) ? wy : 1.f - wy);
            bool valid = (xc >= 0) && (xc < WW) && (yc >= 0) && (yc < HH);
            int xcc = min(max(xc, 0), WW - 1), ycc = min(max(yc, 0), HH - 1);
            poff[t * 4 + j] = ((b * HH + ycc) * WW + xcc) * C2D;
            pwgt[t * 4 + j] = valid ? wgt : 0.f;
        }
    }
    __syncthreads();

    // ---- phase 2: GEMM1 A-frags (then xs is dead -> combs may be written) ----
    s16x8 af0 = *(const s16x8*)(xs + (m0 + l15) * 72 + lq * 8);
    s16x8 af1 = *(const s16x8*)(xs + (m0 + l15) * 72 + 32 + lq * 8);
    __syncthreads();

    // ---- phase 3: GEMM1 (K=64) + BN1 + relu -> hs ; bilinear gather -> combs[:,128:] ----
    #pragma unroll
    for (int nt = 0; nt < 8; nt++) {
        f32x4 acc = {0.f, 0.f, 0.f, 0.f};
        s16x8 bf0 = *(const s16x8*)(w1b + (nt * 16 + l15) * 64 + lq * 8);
        s16x8 bf1 = *(const s16x8*)(w1b + (nt * 16 + l15) * 64 + 32 + lq * 8);
        acc = __builtin_amdgcn_mfma_f32_16x16x32_bf16(af0, bf0, acc, 0, 0, 0);
        acc = __builtin_amdgcn_mfma_f32_16x16x32_bf16(af1, bf1, acc, 0, 0, 0);
        int c = nt * 16 + l15;
        float sc = bn1s[c], shf = bn1sh[c];
        #pragma unroll
        for (int r = 0; r < 4; r++) {
            float h = fmaxf(acc[r] * sc + shf, 0.f);
            hs[(m0 + lq * 4 + r) * 136 + c] = f2bf(h);
        }
    }
    {   // gather: thread -> (row r2, channel-quarter qc), bf16 image
        int r2 = t >> 2, qc = t & 3;
        float acc[32];
        #pragma unroll
        for (int i = 0; i < 32; i++) acc[i] = 0.f;
        #pragma unroll
        for (int j = 0; j < 4; j++) {
            float wgt = pwgt[r2 * 4 + j];
            const s16x8* src = (const s16x8*)(img_bf + poff[r2 * 4 + j] + qc * 32);
            #pragma unroll
            for (int q = 0; q < 4; q++) {
                s16x8 v = src[q];
                #pragma unroll
                for (int e = 0; e < 8; e++)
                    acc[q * 8 + e] += wgt * bf2f((ushort)v[e]);
            }
        }
        #pragma unroll
        for (int g = 0; g < 4; g++) {
            s16x8 v;
            #pragma unroll
            for (int e = 0; e < 8; e++) v[e] = (short)f2bf(acc[g * 8 + e]);
            *(s16x8*)(combs + r2 * 264 + 128 + qc * 32 + g * 8) = v;
        }
    }
    __syncthreads();

    // ---- phase 4: GEMM2 (K=128) + b2 -> combs[:, :128] ----
    {
        s16x8 af[4];
        #pragma unroll
        for (int s = 0; s < 4; s++)
            af[s] = *(const s16x8*)(hs + (m0 + l15) * 136 + s * 32 + lq * 8);
        #pragma unroll
        for (int nt = 0; nt < 8; nt++) {
            f32x4 acc = {0.f, 0.f, 0.f, 0.f};
            #pragma unroll
            for (int s = 0; s < 4; s++) {
                s16x8 bf = *(const s16x8*)(w2b + (nt * 16 + l15) * 128 + s * 32 + lq * 8);
                acc = __builtin_amdgcn_mfma_f32_16x16x32_bf16(af[s], bf, acc, 0, 0, 0);
            }
            int c = nt * 16 + l15;
            float bb = b2[c];
            #pragma unroll
            for (int r = 0; r < 4; r++)
                combs[(m0 + lq * 4 + r) * 264 + c] = f2bf(acc[r] + bb);
        }
    }
    __syncthreads();

    // ---- phase 5: att1 (K=256) + ab1 + relu -> hs ----
    {
        s16x8 af[8];
        #pragma unroll
        for (int s = 0; s < 8; s++)
            af[s] = *(const s16x8*)(combs + (m0 + l15) * 264 + s * 32 + lq * 8);
        #pragma unroll
        for (int nt = 0; nt < 8; nt++) {
            f32x4 acc = {0.f, 0.f, 0.f, 0.f};
            #pragma unroll
            for (int s = 0; s < 8; s++) {
                s16x8 bf = *(const s16x8*)(aw1b + (nt * 16 + l15) * 256 + s * 32 + lq * 8);
                acc = __builtin_amdgcn_mfma_f32_16x16x32_bf16(af[s], bf, acc, 0, 0, 0);
            }
            int c = nt * 16 + l15;
            float bb = ab1[c];
            #pragma unroll
            for (int r = 0; r < 4; r++)
                hs[(m0 + lq * 4 + r) * 136 + c] = f2bf(fmaxf(acc[r] + bb, 0.f));
        }
    }
    __syncthreads();

    // ---- phase 6: att2 + sigmoid -> a_s ----
    if (t < 64) {
        float z = ab2[0];
        #pragma unroll 4
        for (int j = 0; j < 16; j++) {
            s16x8 hv = *(const s16x8*)(hs + t * 136 + j * 8);
            s16x8 wv = *(const s16x8*)(aw2b + j * 8);
            #pragma unroll
            for (int e = 0; e < 8; e++)
                z += bf2f((ushort)hv[e]) * bf2f((ushort)wv[e]);
        }
        a_s[t] = 1.f / (1.f + expf(-z));
    }
    __syncthreads();

    // ---- phase 7: gate combs in place (vfeat *= a, ifeat *= 1-a) ----
    {
        int row = t >> 2, q = t & 3;
        float f = (q < 2) ? a_s[row] : 1.f - a_s[row];
        ushort* p = combs + row * 264 + q * 64;
        #pragma unroll
        for (int j = 0; j < 8; j++) {
            s16x8 v = *(s16x8*)(p + j * 8);
            s16x8 o;
            #pragma unroll
            for (int e = 0; e < 8; e++) o[e] = (short)f2bf(bf2f((ushort)v[e]) * f);
            *(s16x8*)(p + j * 8) = o;
        }
    }
    __syncthreads();

    // ---- phase 8: fusion GEMM (K=256), keep acc in regs ----
    f32x4 facc[8];
    {
        s16x8 af[8];
        #pragma unroll
        for (int s = 0; s < 8; s++)
            af[s] = *(const s16x8*)(combs + (m0 + l15) * 264 + s * 32 + lq * 8);
        #pragma unroll
        for (int nt = 0; nt < 8; nt++) {
            f32x4 acc = {0.f, 0.f, 0.f, 0.f};
            #pragma unroll
            for (int s = 0; s < 8; s++) {
                s16x8 bf = *(const s16x8*)(fwb + (nt * 16 + l15) * 256 + s * 32 + lq * 8);
                acc = __builtin_amdgcn_mfma_f32_16x16x32_bf16(af[s], bf, acc, 0, 0, 0);
            }
            facc[nt] = acc;
        }
    }
    __syncthreads();   // all combs reads done -> outs may overwrite

    // ---- phase 9: acc + fb -> outs (f32, pitch 132) ----
    #pragma unroll
    for (int nt = 0; nt < 8; nt++) {
        int c = nt * 16 + l15;
        float bb = fb[c];
        #pragma unroll
        for (int r = 0; r < 4; r++)
            outs[(m0 + lq * 4 + r) * 132 + c] = facc[nt][r] + bb;
    }
    __syncthreads();

    // ---- phase 10: coalesced global store + BN2 stats (fixed-point u64) ----
    {
        float4* og = (float4*)(out + (long)n0 * OUTC);
        #pragma unroll
        for (int i = 0; i < 8; i++) {
            int f4 = t + 256 * i;              // 2048 float4 = 64 rows x 32
            int row = f4 >> 5, c4 = f4 & 31;
            float4 v = *(const float4*)(outs + row * 132 + c4 * 4);
            og[row * 32 + c4] = v;
        }
        int slot = blockIdx.x & 15;
        if (t < 128) {
            float S = 0.f;
            #pragma unroll 8
            for (int row = 0; row < 64; row++) S += outs[row * 132 + t];
            atomic_fx(&sum64[t * 16 + slot], S);
        } else {
            int c = t - 128;
            float Q = 0.f;
            #pragma unroll 8
            for (int row = 0; row < 64; row++) { float v = outs[row * 132 + c]; Q += v * v; }
            atomic_fx(&ssq64[c * 16 + slot], Q);
        }
    }
}

// ---------------------------------------------------------------------------
// K6: in-place BN2 + relu on d_out
// ---------------------------------------------------------------------------
__global__ __launch_bounds__(256) void k_bnf(float* __restrict__ out,
                                             const float* __restrict__ s,
                                             const float* __restrict__ sh) {
    long i = (long)blockIdx.x * 256 + threadIdx.x;   // over 6.4M float4
    float4* p = (float4*)out;
    float4 v = p[i];
    int c4 = (int)(i & 31);
    float4 sv  = ((const float4*)s)[c4];
    float4 shv = ((const float4*)sh)[c4];
    v.x = fmaxf(v.x * sv.x + shv.x, 0.f);
    v.y = fmaxf(v.y * sv.y + shv.y, 0.f);
    v.z = fmaxf(v.z * sv.z + shv.z, 0.f);
    v.w = fmaxf(v.w * sv.w + shv.w, 0.f);
    p[i] = v;
}

// ---------------------------------------------------------------------------
extern "C" void kernel_launch(void* const* d_in, const int* in_sizes, int n_in,
                              void* d_out, int out_size, void* d_ws, size_t ws_size,
                              hipStream_t stream) {
    const float* x      = (const float*)d_in[0];
    const int*   coords = (const int*)d_in[1];
    const float* img    = (const float*)d_in[2];
    const float* P2     = (const float*)d_in[3];
    const float* w1     = (const float*)d_in[4];
    const float* b1     = (const float*)d_in[5];
    const float* g1     = (const float*)d_in[6];
    const float* be1    = (const float*)d_in[7];
    const float* w2     = (const float*)d_in[8];
    const float* b2     = (const float*)d_in[9];
    const float* aw1    = (const float*)d_in[10];
    const float* ab1    = (const float*)d_in[11];
    const float* aw2    = (const float*)d_in[12];
    const float* ab2    = (const float*)d_in[13];
    const float* fw     = (const float*)d_in[14];
    const float* fb     = (const float*)d_in[15];
    const float* gf     = (const float*)d_in[16];
    const float* bef    = (const float*)d_in[17];
    float* out = (float*)d_out;

    float* wsf = (float*)d_ws;
    ushort* wb = (ushort*)wsf;                                   // 90240 ushorts
    unsigned long long* S64   = (unsigned long long*)(wsf + WS_S64);
    unsigned long long* cs64  = (unsigned long long*)(wsf + WS_CS64);
    unsigned long long* sum64 = (unsigned long long*)(wsf + WS_SUM64);
    unsigned long long* ssq64 = (unsigned long long*)(wsf + WS_SSQ64);
    float* zero_base = wsf + WS_S64;
    float* s1  = wsf + WS_DERIV;
    float* sh1 = s1 + 128;
    float* s2  = sh1 + 128;
    float* sh2 = s2 + 128;
    ushort* img_bf = (ushort*)(wsf + WS_IMG);                    // 15,335,424 ushorts

    // K1: transpose image (bf16) + zero stats region
    k_transpose<<<BB * HH * 10 * 4, 256, 0, stream>>>(img, img_bf, zero_base);
    // K1b: bf16 weights
    k_prepw<<<(WB_TOTAL + 255) / 256, 256, 0, stream>>>(w1, w2, aw1, aw2, fw, wb);
    // K2: X^T X + colsum (u64 fixed-point atomics, deterministic)
    k_xtx<<<XTX_BLOCKS, 256, 0, stream>>>(x, S64, cs64);
    // K3: finalize BN1 (algebraic, b1 folded)
    k_finalize1<<<1, 128, 0, stream>>>(S64, cs64, w1, b1, g1, be1, s1, sh1);
    // K4: fused main (MFMA), 3125 blocks
    k_main<<<NPTS / 64, 256, 0, stream>>>(x, coords, img_bf, P2, wb, s1, sh1,
                                          b2, ab1, ab2, fb, out, sum64, ssq64);
    // K5: finalize BN2 (fixed-order slot reduce)
    k_finalize<<<1, 128, 0, stream>>>(sum64, ssq64, gf, bef, s2, sh2);
    // K6: in-place BN2 + relu
    k_bnf<<<NPTS * OUTC / 4 / 256, 256, 0, stream>>>(out, s2, sh2);
}